// Round 1
// baseline (707.887 us; speedup 1.0000x reference)
//
#include <hip/hip_runtime.h>
#include <hip/hip_bf16.h>
#include <cstdint>
#include <cstddef>

#define N 4096
#define NN ((size_t)N * (size_t)N)
#define LDA 72   // LDS row stride in shorts: 144B = 9*16B (b128-aligned), 4m%32 bank spread -> <=2-way

typedef short short8 __attribute__((ext_vector_type(8)));
typedef float floatx4 __attribute__((ext_vector_type(4)));

// ---------------- kernel 1: straight-through relaxed Bernoulli flip ----------------
__global__ void mod_kernel(const float* __restrict__ ori,
                           const float* __restrict__ clp,
                           const float* __restrict__ u,
                           float* __restrict__ out) {
    size_t i = (size_t)blockIdx.x * blockDim.x + threadIdx.x;
    if (i >= NN) return;
    float p = clp[i];
    p = fminf(fmaxf(p, 1e-10f), 1.0f - 1e-10f);
    float logits = logf(p) - log1pf(-p);
    float uu = u[i];
    float noise = logf(uu) - log1pf(-uu);
    float y = (logits + noise) / 0.2f;          // TAU = 0.2, division to match np
    float soft = 1.0f / (1.0f + expf(-y));
    float hard = rintf(soft);                   // np.round = half-even = rint
    float o = ori[i];
    out[i] = o + hard * (-2.0f * o);            // ori * (1 - 2*hard), exact {-1,0,1}
}

// ---------------- kernel 2: diagonal extract + zero the trace accumulators ----------------
__global__ void diag_kernel(const float* __restrict__ mod,
                            float* __restrict__ diag,
                            double* __restrict__ accs) {
    int j = blockIdx.x * blockDim.x + threadIdx.x;
    if (j < N) diag[j] = mod[(size_t)j * N + j];
    if (blockIdx.x == 0 && threadIdx.x < 2) accs[threadIdx.x] = 0.0;
}

// ---------------- kernel 3: A = mod + mod^T - diag(col), bf16, plus transposed copy ----------------
__global__ void build_A(const float* __restrict__ mod,
                        const float* __restrict__ diag,
                        __hip_bfloat16* __restrict__ A,
                        __hip_bfloat16* __restrict__ AT) {
    __shared__ float tji[32][33];
    __shared__ __hip_bfloat16 atile[32][33];
    const int bi = blockIdx.x * 32;
    const int bj = blockIdx.y * 32;
    const int tx = threadIdx.x;   // 0..31
    const int ty = threadIdx.y;   // 0..7
    for (int rr = ty; rr < 32; rr += 8)
        tji[rr][tx] = mod[(size_t)(bj + rr) * N + bi + tx];   // mod[j-range][i-range], coalesced
    float dj = diag[bj + tx];
    __syncthreads();
    for (int rr = ty; rr < 32; rr += 8) {
        int i = bi + rr, j = bj + tx;
        float a = mod[(size_t)i * N + j] + tji[tx][rr] - dj;  // A[i][j] in [-3,3] integer
        __hip_bfloat16 ab = __float2bfloat16(a);              // exact
        A[(size_t)i * N + j] = ab;
        atile[tx][rr] = ab;                                    // atile[jj][ii]
    }
    __syncthreads();
    for (int rr = ty; rr < 32; rr += 8)
        AT[(size_t)(bj + rr) * N + bi + tx] = atile[rr][tx];  // AT[j][i] = A[i][j], coalesced
}

// ---------------- kernel 4: GEMM-trace: acc[z] += sum_{i,k} (M.M)[i,k] * M[k,i], M = A (z=0) or |A| (z=1) ----
__global__ __launch_bounds__(256) void gemm_trace(const __hip_bfloat16* __restrict__ A,
                                                  const __hip_bfloat16* __restrict__ AT,
                                                  double* __restrict__ accs) {
    __shared__ short As[128 * LDA];   // [m][k], k contiguous
    __shared__ short Bs[128 * LDA];   // [n][k], k contiguous (B[k][n] = AT[n][k])
    __shared__ float red[4];
    const int z = blockIdx.z;
    const unsigned mask = z ? 0x7fff7fffu : 0xffffffffu;   // |bf16| = clear sign bit
    const int i0 = blockIdx.y * 128;
    const int k0 = blockIdx.x * 128;
    const int t = threadIdx.x;
    const int lane = t & 63;
    const int wave = t >> 6;
    const int quad = lane >> 4;
    const int col  = lane & 15;
    const int wr = (wave >> 1) * 64;
    const int wc = (wave & 1) * 64;
    const short* Ag  = (const short*)A;
    const short* ATg = (const short*)AT;

    floatx4 acc[4][4];
    #pragma unroll
    for (int a = 0; a < 4; ++a)
        #pragma unroll
        for (int b = 0; b < 4; ++b)
            acc[a][b] = (floatx4){0.f, 0.f, 0.f, 0.f};

    for (int kb = 0; kb < N; kb += 32) {
        __syncthreads();
        #pragma unroll
        for (int it = 0; it < 2; ++it) {
            int c = t + it * 256;          // 512 chunks of 16B per matrix
            int row = c >> 2;              // 0..127
            int cc  = (c & 3) * 8;         // short offset within 32-wide K tile
            int4 va = *(const int4*)(Ag + (size_t)(i0 + row) * N + kb + cc);
            va.x &= mask; va.y &= mask; va.z &= mask; va.w &= mask;
            *(int4*)(&As[row * LDA + cc]) = va;
            int4 vb = *(const int4*)(ATg + (size_t)(k0 + row) * N + kb + cc);
            vb.x &= mask; vb.y &= mask; vb.z &= mask; vb.w &= mask;
            *(int4*)(&Bs[row * LDA + cc]) = vb;
        }
        __syncthreads();
        short8 af[4], bf[4];
        #pragma unroll
        for (int tr = 0; tr < 4; ++tr)   // A[m = lane&15][k = quad*8 + j]
            af[tr] = *(const short8*)(&As[(wr + tr * 16 + col) * LDA + quad * 8]);
        #pragma unroll
        for (int tc = 0; tc < 4; ++tc)   // B[k = quad*8 + j][n = lane&15]
            bf[tc] = *(const short8*)(&Bs[(wc + tc * 16 + col) * LDA + quad * 8]);
        #pragma unroll
        for (int tr = 0; tr < 4; ++tr)
            #pragma unroll
            for (int tc = 0; tc < 4; ++tc)
                acc[tr][tc] = __builtin_amdgcn_mfma_f32_16x16x32_bf16(af[tr], bf[tc], acc[tr][tc], 0, 0, 0);
    }

    // trace epilogue: C/D layout col=lane&15, row=quad*4+reg; multiplier A[k,i] = AT[i,k]
    float part = 0.f;
    #pragma unroll
    for (int tr = 0; tr < 4; ++tr) {
        #pragma unroll
        for (int tc = 0; tc < 4; ++tc) {
            int ib = i0 + wr + tr * 16 + quad * 4;
            int kk = k0 + wc + tc * 16 + col;
            #pragma unroll
            for (int r = 0; r < 4; ++r) {
                float m = __bfloat162float(AT[(size_t)(ib + r) * N + kk]);
                if (z) m = fabsf(m);
                part += acc[tr][tc][r] * m;
            }
        }
    }
    #pragma unroll
    for (int off = 32; off > 0; off >>= 1)
        part += __shfl_down(part, off, 64);
    if (lane == 0) red[wave] = part;
    __syncthreads();
    if (t == 0) {
        float tot = red[0] + red[1] + red[2] + red[3];
        atomicAdd(&accs[z], (double)tot);
    }
}

// ---------------- kernel 5: balance ----------------
__global__ void finalize_kernel(const double* __restrict__ accs, float* __restrict__ out) {
    out[NN] = (float)(0.5 * (1.0 + accs[0] / accs[1]));
}

extern "C" void kernel_launch(void* const* d_in, const int* in_sizes, int n_in,
                              void* d_out, int out_size, void* d_ws, size_t ws_size,
                              hipStream_t stream) {
    const float* ori = (const float*)d_in[0];
    const float* clp = (const float*)d_in[1];
    const float* u   = (const float*)d_in[2];
    float* out = (float*)d_out;
    char* ws = (char*)d_ws;
    __hip_bfloat16* A    = (__hip_bfloat16*)ws;                 // 32 MiB
    __hip_bfloat16* AT   = (__hip_bfloat16*)(ws + NN * 2);      // 32 MiB
    float*          diag = (float*)(ws + NN * 4);               // 16 KiB
    double*         accs = (double*)(ws + NN * 4 + 4096 * 4);   // 16 B

    mod_kernel<<<dim3((unsigned)(NN / 256)), 256, 0, stream>>>(ori, clp, u, out);
    diag_kernel<<<dim3(16), 256, 0, stream>>>(out, diag, accs);
    build_A<<<dim3(N / 32, N / 32), dim3(32, 8), 0, stream>>>(out, diag, A, AT);
    gemm_trace<<<dim3(N / 128, N / 128, 2), 256, 0, stream>>>(A, AT, accs);
    finalize_kernel<<<1, 1, 0, stream>>>(accs, out);
}

// Round 2
// 427.004 us; speedup vs baseline: 1.6578x; 1.6578x over previous
//
#include <hip/hip_runtime.h>
#include <hip/hip_bf16.h>
#include <cstdint>
#include <cstddef>

#define N 4096
#define NN ((size_t)N * (size_t)N)

typedef int int4v __attribute__((ext_vector_type(4)));

__device__ inline void async16(const void* g, void* lds) {
    __builtin_amdgcn_global_load_lds(
        (const __attribute__((address_space(1))) void*)g,
        (__attribute__((address_space(3))) void*)lds, 16, 0, 0);
}

// ---------------- kernel 1: straight-through relaxed Bernoulli flip (unchanged, proven exact) ---
__global__ void mod_kernel(const float* __restrict__ ori,
                           const float* __restrict__ clp,
                           const float* __restrict__ u,
                           float* __restrict__ out) {
    size_t i = (size_t)blockIdx.x * blockDim.x + threadIdx.x;
    if (i >= NN) return;
    float p = clp[i];
    p = fminf(fmaxf(p, 1e-10f), 1.0f - 1e-10f);
    float logits = logf(p) - log1pf(-p);
    float uu = u[i];
    float noise = logf(uu) - log1pf(-uu);
    float y = (logits + noise) / 0.2f;
    float soft = 1.0f / (1.0f + expf(-y));
    float hard = rintf(soft);
    float o = ori[i];
    out[i] = o + hard * (-2.0f * o);
}

// ---------------- kernel 2: diagonal extract + zero accumulators ----------------
__global__ void diag_kernel(const float* __restrict__ mod,
                            float* __restrict__ diag,
                            double* __restrict__ accs) {
    int j = blockIdx.x * blockDim.x + threadIdx.x;
    if (j < N) diag[j] = mod[(size_t)j * N + j];
    if (blockIdx.x == 0 && threadIdx.x < 2) accs[threadIdx.x] = 0.0;
}

// ---------------- kernel 3: A = mod + mod^T - diag(col) as i8: A, AT, |A|, |A|T ----------------
__global__ void build_A8(const float* __restrict__ mod,
                         const float* __restrict__ diag,
                         signed char* __restrict__ A,
                         signed char* __restrict__ AT,
                         signed char* __restrict__ Aa,
                         signed char* __restrict__ ATa) {
    __shared__ float tji[32][33];        // tji[j-local][i-local] = mod[j][i]
    __shared__ signed char cv[32][36];   // cv[i-local][j-local] = A value
    const int bi = blockIdx.x * 32;
    const int bj = blockIdx.y * 32;
    const int tx = threadIdx.x;   // 0..7  (groups of 4 cols)
    const int ty = threadIdx.y;   // 0..31 (rows)
    {
        const float4 v = *(const float4*)&mod[(size_t)(bj + ty) * N + bi + tx * 4];
        tji[ty][tx * 4 + 0] = v.x; tji[ty][tx * 4 + 1] = v.y;
        tji[ty][tx * 4 + 2] = v.z; tji[ty][tx * 4 + 3] = v.w;
    }
    __syncthreads();
    const float4 mv = *(const float4*)&mod[(size_t)(bi + ty) * N + bj + tx * 4];
    float m4[4] = {mv.x, mv.y, mv.z, mv.w};
    int pkA = 0, pkAa = 0;
    #pragma unroll
    for (int k = 0; k < 4; ++k) {
        int jl = tx * 4 + k;
        float a = m4[k] + tji[jl][ty] - diag[bj + jl];  // exact small integer
        int ai = (int)a;
        cv[ty][jl] = (signed char)ai;
        int au = ai < 0 ? -ai : ai;
        pkA  |= (ai & 255) << (8 * k);
        pkAa |= (au & 255) << (8 * k);
    }
    *(int*)&A [(size_t)(bi + ty) * N + bj + tx * 4] = pkA;
    *(int*)&Aa[(size_t)(bi + ty) * N + bj + tx * 4] = pkAa;
    __syncthreads();
    int pkT = 0, pkTa = 0;
    #pragma unroll
    for (int k = 0; k < 4; ++k) {
        int il = tx * 4 + k;
        int v = cv[il][ty];                 // A[i-local=il][j-local=ty] -> AT[j][i]
        int va = v < 0 ? -v : v;
        pkT  |= (v  & 255) << (8 * k);
        pkTa |= (va & 255) << (8 * k);
    }
    *(int*)&AT [(size_t)(bj + ty) * N + bi + tx * 4] = pkT;
    *(int*)&ATa[(size_t)(bj + ty) * N + bi + tx * 4] = pkTa;
}

// ---------------- kernel 4: i8 GEMM-trace with global_load_lds + XOR swizzle ----------------
// acc[z] = sum_{i,k} (M.M)[i,k] * M[k,i], M = A (z=0) or |A| (z=1). Exact integer math.
__global__ __launch_bounds__(256) void gemm_trace_i8(const signed char* __restrict__ Ag,
                                                     const signed char* __restrict__ ATg,
                                                     const signed char* __restrict__ Aag,
                                                     const signed char* __restrict__ ATag,
                                                     double* __restrict__ accs) {
    __shared__ int4v As4[512];   // 128 rows x 64 B, row-major, swizzled slots
    __shared__ int4v Bs4[512];
    __shared__ int red[4];
    const int z = blockIdx.z;
    const signed char* Asrc = z ? Aag  : Ag;    // M rows   (i-panel)
    const signed char* Bsrc = z ? ATag : ATg;   // MT rows  (k-panel), B[k][n] = MT[n][k]
    const int i0 = blockIdx.y * 128;
    const int k0 = blockIdx.x * 128;
    const int t = threadIdx.x;
    const int lane = t & 63;
    const int wave = t >> 6;
    const int quad = lane >> 4;
    const int col  = lane & 15;
    const int wr = (wave >> 1) * 64;
    const int wc = (wave & 1) * 64;
    signed char* Asc = (signed char*)As4;
    signed char* Bsc = (signed char*)Bs4;

    // staging plan: 512 chunks of 16B per matrix; chunk c = it*256 + wave*64 + lane
    // LDS slot (row=c>>2, slot=c&3) holds global chunk slot ^ ((row>>1)&3)
    const int c0 = wave * 64 + lane;
    const int c1 = c0 + 256;
    const int r0 = c0 >> 2, r1 = c1 >> 2;
    const int cc0 = (((c0 & 3) ^ ((r0 >> 1) & 3)) << 4);
    const int cc1 = (((c1 & 3) ^ ((r1 >> 1) & 3)) << 4);
    const int ldsb0 = (wave * 64) << 4;          // wave-uniform LDS base, it=0
    const int ldsb1 = (256 + wave * 64) << 4;    // it=1
    const signed char* gA0 = Asrc + (size_t)(i0 + r0) * N + cc0;
    const signed char* gA1 = Asrc + (size_t)(i0 + r1) * N + cc1;
    const signed char* gB0 = Bsrc + (size_t)(k0 + r0) * N + cc0;
    const signed char* gB1 = Bsrc + (size_t)(k0 + r1) * N + cc1;

    int4v acc[4][4];
    #pragma unroll
    for (int a = 0; a < 4; ++a)
        #pragma unroll
        for (int b = 0; b < 4; ++b)
            acc[a][b] = (int4v){0, 0, 0, 0};

    const int fsw = ((quad ^ ((col >> 1) & 3)) << 4);  // fragment k-slot after swizzle

    for (int kb = 0; kb < N; kb += 64) {
        __syncthreads();
        async16(gA0 + kb, Asc + ldsb0);
        async16(gA1 + kb, Asc + ldsb1);
        async16(gB0 + kb, Bsc + ldsb0);
        async16(gB1 + kb, Bsc + ldsb1);
        __syncthreads();
        int4v af[4], bf[4];
        #pragma unroll
        for (int tr = 0; tr < 4; ++tr)   // A[m = lane&15][k = quad*16 + j]
            af[tr] = *(const int4v*)(Asc + ((wr + tr * 16 + col) << 6) + fsw);
        #pragma unroll
        for (int tc = 0; tc < 4; ++tc)   // B[k = quad*16 + j][n = lane&15]
            bf[tc] = *(const int4v*)(Bsc + ((wc + tc * 16 + col) << 6) + fsw);
        #pragma unroll
        for (int tr = 0; tr < 4; ++tr)
            #pragma unroll
            for (int tc = 0; tc < 4; ++tc)
                acc[tr][tc] = __builtin_amdgcn_mfma_i32_16x16x64_i8(af[tr], bf[tc], acc[tr][tc], 0, 0, 0);
    }

    // trace epilogue: C/D layout col=lane&15, row=quad*4+reg (shape-determined).
    // multiplier M[k,i] = MT[i,k] = Bsrc[i*N + k] (already |.| for z=1). Exact int32.
    int part = 0;
    #pragma unroll
    for (int tr = 0; tr < 4; ++tr) {
        #pragma unroll
        for (int tc = 0; tc < 4; ++tc) {
            const int ib = i0 + wr + tr * 16 + quad * 4;
            const int kk = k0 + wc + tc * 16 + col;
            #pragma unroll
            for (int r = 0; r < 4; ++r)
                part += acc[tr][tc][r] * (int)Bsrc[(size_t)(ib + r) * N + kk];
        }
    }
    #pragma unroll
    for (int off = 32; off > 0; off >>= 1)
        part += __shfl_down(part, off, 64);
    if (lane == 0) red[wave] = part;
    __syncthreads();
    if (t == 0) {
        int tot = red[0] + red[1] + red[2] + red[3];
        atomicAdd(&accs[z], (double)tot);
    }
}

// ---------------- kernel 5: balance ----------------
__global__ void finalize_kernel(const double* __restrict__ accs, float* __restrict__ out) {
    out[NN] = (float)(0.5 * (1.0 + accs[0] / accs[1]));
}

extern "C" void kernel_launch(void* const* d_in, const int* in_sizes, int n_in,
                              void* d_out, int out_size, void* d_ws, size_t ws_size,
                              hipStream_t stream) {
    const float* ori = (const float*)d_in[0];
    const float* clp = (const float*)d_in[1];
    const float* u   = (const float*)d_in[2];
    float* out = (float*)d_out;
    char* ws = (char*)d_ws;
    signed char* A8   = (signed char*)ws;                    // 16 MiB
    signed char* AT8  = (signed char*)(ws + NN);             // 16 MiB
    signed char* Aa8  = (signed char*)(ws + 2 * NN);         // 16 MiB
    signed char* ATa8 = (signed char*)(ws + 3 * NN);         // 16 MiB
    float*       diag = (float*)(ws + 4 * NN);               // 16 KiB
    double*      accs = (double*)(ws + 4 * NN + 4096 * 4);   // 16 B

    mod_kernel<<<dim3((unsigned)(NN / 256)), 256, 0, stream>>>(ori, clp, u, out);
    diag_kernel<<<dim3(16), 256, 0, stream>>>(out, diag, accs);
    build_A8<<<dim3(N / 32, N / 32), dim3(8, 32), 0, stream>>>(out, diag, A8, AT8, Aa8, ATa8);
    gemm_trace_i8<<<dim3(N / 128, N / 128, 2), 256, 0, stream>>>(A8, AT8, Aa8, ATa8, accs);
    finalize_kernel<<<1, 1, 0, stream>>>(accs, out);
}